// Round 4
// baseline (207.375 us; speedup 1.0000x reference)
//
#include <hip/hip_runtime.h>
#include <math.h>

#define BATCH 4
#define SEQ   4096
#define DIM   1024
#define VEC   4

#define SENT 0xFFFFFFFFFFFFFFFFull

static __device__ __forceinline__ unsigned long long pack2(float r, float i) {
    union { float2 f; unsigned long long u; } v;
    v.f = make_float2(r, i);
    return v.u;
}
static __device__ __forceinline__ float2 unpack2(unsigned long long u) {
    union { float2 f; unsigned long long u; } v;
    v.u = u;
    return v.f;
}

// Per-d parameters: a = phazor = p/|p| * exp(-|p|), b = phazor_init.
__device__ __forceinline__ void load_params4(
    const float* __restrict__ phr, const float* __restrict__ phi,
    const float* __restrict__ pir, const float* __restrict__ pii,
    int d0, float* ar, float* ai, float* br, float* bi)
{
    float4 p_r = *reinterpret_cast<const float4*>(phr + d0);
    float4 p_i = *reinterpret_cast<const float4*>(phi + d0);
    float4 q_r = *reinterpret_cast<const float4*>(pir + d0);
    float4 q_i = *reinterpret_cast<const float4*>(pii + d0);
    float prv[VEC] = {p_r.x, p_r.y, p_r.z, p_r.w};
    float piv[VEC] = {p_i.x, p_i.y, p_i.z, p_i.w};
    float qrv[VEC] = {q_r.x, q_r.y, q_r.z, q_r.w};
    float qiv[VEC] = {q_i.x, q_i.y, q_i.z, q_i.w};
#pragma unroll
    for (int j = 0; j < VEC; ++j) {
        float mag = sqrtf(prv[j] * prv[j] + piv[j] * piv[j]);
        float s = expf(-mag) / mag;
        ar[j] = prv[j] * s;
        ai[j] = piv[j] * s;
        br[j] = qrv[j];
        bi[j] = qiv[j];
    }
}

// Single-pass decoupled-lookback scan.
// Block = one (chunk c, batch b); 256 threads x VEC=4 d's = DIM.
// agg[b][c][d] : local chunk carry (zero-init scan), published unconditionally.
// pre[b][c][d] : inclusive state after chunk c (given hidden seed).
// Both arrays are pre-memset to 0xFF (NaN:NaN) = SENT; an 8-byte agent-scope
// atomic store of the real value IS the flag (values are never NaN).
// Lookback only waits on lower block ids -> forward progress under in-order
// dispatch (same assumption rocPRIM's single-pass scan ships with).
template <int NC, bool CPLX>
__global__ __launch_bounds__(256, 4) void k_fused(
    const float* __restrict__ x,
    const float* __restrict__ phr, const float* __restrict__ phi,
    const float* __restrict__ pir, const float* __restrict__ pii,
    const float* __restrict__ hr,  const float* __restrict__ hi_,
    unsigned long long* __restrict__ agg,
    unsigned long long* __restrict__ pre,
    float* __restrict__ out)
{
    constexpr int S = SEQ / NC;
    const int bid = blockIdx.x;
    const int c = bid / BATCH, b = bid % BATCH;   // chunk-major: block waits only on lower bids
    const int d0 = threadIdx.x * VEC;

    float ar[VEC], ai[VEC], br[VEC], bi[VEC];
    load_params4(phr, phi, pir, pii, d0, ar, ai, br, bi);

    // Phase 1: zero-init local scan over this chunk.
    const float* xp = x + ((size_t)b * SEQ + (size_t)c * S) * DIM + d0;
    float Cr[VEC] = {0.f, 0.f, 0.f, 0.f};
    float Ci[VEC] = {0.f, 0.f, 0.f, 0.f};
#pragma unroll 4
    for (int t = 0; t < S; ++t) {
        float4 xv = *reinterpret_cast<const float4*>(xp + (size_t)t * DIM);
        float xa[VEC] = {xv.x, xv.y, xv.z, xv.w};
#pragma unroll
        for (int j = 0; j < VEC; ++j) {
            float nr = fmaf(ar[j], Cr[j], fmaf(-ai[j], Ci[j], br[j] * xa[j]));
            float ni = fmaf(ar[j], Ci[j], fmaf( ai[j], Cr[j], bi[j] * xa[j]));
            Cr[j] = nr; Ci[j] = ni;
        }
    }

    // Publish aggregate (local carry).
    const size_t lbase = ((size_t)b * NC + c) * DIM + d0;
#pragma unroll
    for (int j = 0; j < VEC; ++j)
        __hip_atomic_store(&agg[lbase + j], pack2(Cr[j], Ci[j]),
                           __ATOMIC_RELAXED, __HIP_MEMORY_SCOPE_AGENT);

    // A = a^S per d (exponentiation by squaring).
    float Ar[VEC], Ai[VEC];
#pragma unroll
    for (int j = 0; j < VEC; ++j) {
        float mr = 1.f, mi = 0.f, sr = ar[j], si = ai[j];
        int e = S;
        while (e) {
            if (e & 1) { float nr = mr * sr - mi * si; mi = mr * si + mi * sr; mr = nr; }
            float nr = sr * sr - si * si; si = 2.f * sr * si; sr = nr;
            e >>= 1;
        }
        Ar[j] = mr; Ai[j] = mi;
    }

    // Lookback: state before this chunk.
    float Pr[VEC], Pi[VEC];
    if (c == 0) {
#pragma unroll
        for (int j = 0; j < VEC; ++j) {
            Pr[j] = hr[b * DIM + d0 + j];
            Pi[j] = hi_[b * DIM + d0 + j];
        }
    } else {
        float aR[VEC] = {0.f,0.f,0.f,0.f}, aI[VEC] = {0.f,0.f,0.f,0.f};
        float WR[VEC] = {1.f,1.f,1.f,1.f}, WI[VEC] = {0.f,0.f,0.f,0.f};
        int j = c - 1;
        for (;;) {
            const size_t pbase = ((size_t)b * NC + j) * DIM + d0;
            unsigned long long pv[VEC];
            bool got = true;
#pragma unroll
            for (int jj = 0; jj < VEC; ++jj) {
                pv[jj] = __hip_atomic_load(&pre[pbase + jj],
                                           __ATOMIC_RELAXED, __HIP_MEMORY_SCOPE_AGENT);
                got = got && (pv[jj] != SENT);
            }
            if (got) {
                // P = acc + W * state_after(j)
#pragma unroll
                for (int jj = 0; jj < VEC; ++jj) {
                    float2 v = unpack2(pv[jj]);
                    Pr[jj] = aR[jj] + WR[jj] * v.x - WI[jj] * v.y;
                    Pi[jj] = aI[jj] + WR[jj] * v.y + WI[jj] * v.x;
                }
                break;
            }
            // Consume aggregate of chunk j (spin until published).
#pragma unroll
            for (int jj = 0; jj < VEC; ++jj) {
                unsigned long long av;
                do {
                    av = __hip_atomic_load(&agg[pbase + jj],
                                           __ATOMIC_RELAXED, __HIP_MEMORY_SCOPE_AGENT);
                } while (av == SENT);
                float2 L = unpack2(av);
                aR[jj] += WR[jj] * L.x - WI[jj] * L.y;
                aI[jj] += WR[jj] * L.y + WI[jj] * L.x;
                float nWR = WR[jj] * Ar[jj] - WI[jj] * Ai[jj];
                WI[jj] = WR[jj] * Ai[jj] + WI[jj] * Ar[jj];
                WR[jj] = nWR;
            }
            if (--j < 0) {
                // Consumed all aggregates: P = acc + W * hidden.
#pragma unroll
                for (int jj = 0; jj < VEC; ++jj) {
                    float h_r = hr[b * DIM + d0 + jj];
                    float h_i = hi_[b * DIM + d0 + jj];
                    Pr[jj] = aR[jj] + WR[jj] * h_r - WI[jj] * h_i;
                    Pi[jj] = aI[jj] + WR[jj] * h_i + WI[jj] * h_r;
                }
                break;
            }
        }
    }

    // Phase 2: replay chunk seeded with P (x tile is L1/L2-warm), write out.
#pragma unroll
    for (int j = 0; j < VEC; ++j) { Cr[j] = Pr[j]; Ci[j] = Pi[j]; }

    const size_t obase = ((size_t)b * SEQ + (size_t)c * S) * DIM + d0;
#pragma unroll 2
    for (int t = 0; t < S; ++t) {
        float4 xv = *reinterpret_cast<const float4*>(xp + (size_t)t * DIM);
        float xa[VEC] = {xv.x, xv.y, xv.z, xv.w};
#pragma unroll
        for (int j = 0; j < VEC; ++j) {
            float nr = fmaf(ar[j], Cr[j], fmaf(-ai[j], Ci[j], br[j] * xa[j]));
            float ni = fmaf(ar[j], Ci[j], fmaf( ai[j], Cr[j], bi[j] * xa[j]));
            Cr[j] = nr; Ci[j] = ni;
        }
        if (CPLX) {
            float4* dst = reinterpret_cast<float4*>(out + 2 * (obase + (size_t)t * DIM));
            dst[0] = make_float4(Cr[0], Ci[0], Cr[1], Ci[1]);
            dst[1] = make_float4(Cr[2], Ci[2], Cr[3], Ci[3]);
        } else {
            *reinterpret_cast<float4*>(out + obase + (size_t)t * DIM) =
                make_float4(Cr[0], Cr[1], Cr[2], Cr[3]);
        }
    }

    // Publish inclusive state (not needed for the last chunk).
    if (c < NC - 1) {
#pragma unroll
        for (int j = 0; j < VEC; ++j)
            __hip_atomic_store(&pre[lbase + j], pack2(Cr[j], Ci[j]),
                               __ATOMIC_RELAXED, __HIP_MEMORY_SCOPE_AGENT);
    }
}

// Scratch-free fallback: one thread per (b,d), serial scan over all of SEQ.
template <bool CPLX>
__global__ void k_serial(
    const float* __restrict__ x,
    const float* __restrict__ phr, const float* __restrict__ phi,
    const float* __restrict__ pir, const float* __restrict__ pii,
    const float* __restrict__ hr,  const float* __restrict__ hi_,
    float* __restrict__ out)
{
    const int idx = blockIdx.x * blockDim.x + threadIdx.x;  // b*DIM + d
    if (idx >= BATCH * DIM) return;
    const int b = idx / DIM, d = idx % DIM;

    float pr = phr[d], pi = phi[d];
    float mag = sqrtf(pr * pr + pi * pi);
    float sc = expf(-mag) / mag;
    float ar = pr * sc, ai = pi * sc;
    float br = pir[d], bi = pii[d];

    float Cr = hr[idx], Ci = hi_[idx];
    const float* xp = x + (size_t)b * SEQ * DIM + d;
    for (int t = 0; t < SEQ; ++t) {
        float xv = xp[(size_t)t * DIM];
        float nr = fmaf(ar, Cr, fmaf(-ai, Ci, br * xv));
        float ni = fmaf(ar, Ci, fmaf( ai, Cr, bi * xv));
        Cr = nr; Ci = ni;
        size_t o = ((size_t)b * SEQ + t) * DIM + d;
        if (CPLX) {
            reinterpret_cast<float2*>(out)[o] = make_float2(Cr, Ci);
        } else {
            out[o] = Cr;
        }
    }
}

template <int NC, bool CPLX>
static void run_fused(const float* x, const float* hr, const float* hi_,
                      const float* phr, const float* phi,
                      const float* pir, const float* pii,
                      float* out, void* d_ws, hipStream_t stream)
{
    const size_t n = (size_t)BATCH * NC * DIM;
    unsigned long long* agg = (unsigned long long*)d_ws;
    unsigned long long* pre = agg + n;
    // 0xFF per byte -> SENT in every slot of agg/pre.
    hipMemsetAsync(d_ws, 0xFF, 2 * n * sizeof(unsigned long long), stream);
    k_fused<NC, CPLX><<<dim3(NC * BATCH), dim3(256), 0, stream>>>(
        x, phr, phi, pir, pii, hr, hi_, agg, pre, out);
}

template <bool CPLX>
static void dispatch(const float* x, const float* hr, const float* hi_,
                     const float* phr, const float* phi,
                     const float* pir, const float* pii,
                     float* out, void* d_ws, size_t ws_size, hipStream_t stream)
{
    auto need = [](int nc) {
        return (size_t)2 * BATCH * nc * DIM * sizeof(unsigned long long);
    };
    if (ws_size >= need(256))
        run_fused<256, CPLX>(x, hr, hi_, phr, phi, pir, pii, out, d_ws, stream);
    else if (ws_size >= need(128))
        run_fused<128, CPLX>(x, hr, hi_, phr, phi, pir, pii, out, d_ws, stream);
    else if (ws_size >= need(64))
        run_fused<64, CPLX>(x, hr, hi_, phr, phi, pir, pii, out, d_ws, stream);
    else
        k_serial<CPLX><<<dim3((BATCH * DIM + 255) / 256), dim3(256), 0, stream>>>(
            x, phr, phi, pir, pii, hr, hi_, out);
}

extern "C" void kernel_launch(void* const* d_in, const int* in_sizes, int n_in,
                              void* d_out, int out_size, void* d_ws, size_t ws_size,
                              hipStream_t stream) {
    const float* x   = (const float*)d_in[0];
    const float* hr  = (const float*)d_in[1];
    const float* hi_ = (const float*)d_in[2];
    const float* phr = (const float*)d_in[3];
    const float* phi = (const float*)d_in[4];
    const float* pir = (const float*)d_in[5];
    const float* pii = (const float*)d_in[6];
    float* out = (float*)d_out;

    const size_t total = (size_t)BATCH * SEQ * DIM;
    if ((size_t)out_size >= 2 * total)
        dispatch<true >(x, hr, hi_, phr, phi, pir, pii, out, d_ws, ws_size, stream);
    else
        dispatch<false>(x, hr, hi_, phr, phi, pir, pii, out, d_ws, ws_size, stream);
}